// Round 3
// baseline (504.308 us; speedup 1.0000x reference)
//
#include <hip/hip_runtime.h>
#include <hip/hip_bf16.h>
#include <stdint.h>

// ---------------------------------------------------------------------------
// LBConv: y = fc(relu(conv3x3_ternary(x))) + b
//   x        : [32][256][56][56] f32
//   binary_w : [512][256][3][3]  f32 (ternary)
//   fc_w     : [256][512]        f32
//   fc_b     : [256]             f32
//   out      : [32][256][56][56] f32
//
// R5 changes vs R4 (485us total; conv1 257us @ MfmaUtil 46%):
//  - conv1 inner loop switched 16x16x32 -> 32x32x16 MFMA. Per-CU per-K-step:
//    MFMA pipe 2483->2066 cyc (m119: 32x32 is ~15% faster/FLOP), LDS-read
//    pipe 28->24 ds_read_b128 per wave (448->384 B/lane) -- LDS reads were
//    the critical pipe. LDS/staging layouts unchanged: [khi][row64][klo8]
//    serves 32x32x16 frags directly (lane: row=l&31, k=(l>>5)*8+klo;
//    C/D col=l&31, row=(r&3)+8*(r>>2)+4*(l>>5) re-packs to same Y format).
//  - 2-deep fragment pipeline (named x/y sets): k-sub reads issue under the
//    previous k-sub's MFMAs.
//  - R4's 1-barrier-per-step structure, grid 896, staging all unchanged.
//  - conv2/preps unchanged.
// ---------------------------------------------------------------------------

typedef __attribute__((ext_vector_type(8))) short short8;
typedef __attribute__((ext_vector_type(4))) float floatx4;
typedef __attribute__((ext_vector_type(16))) float floatx16;

#define ROWE 8192            // elems per padded row per (b,cg): 16*64*8
#define NT_PER_B 28          // 3584/128 (old 2-row ntiles, still used by conv2)

// workspace byte offsets
#define OFF_WP  0            // 9*2*512*128*2        = 2,359,296
#define OFF_A2  2359296      // 4*2*128*128*2        =   262,144
#define OFF_XP  2621440      // 64*58*8192*2         = 60,817,408
#define OFF_Y   63439872     // 896*4*16384*2        = 117,440,512
// total required ws: 180,880,384 bytes (~173 MB)

__device__ static inline void async16(const void* gptr, void* lptr) {
  __builtin_amdgcn_global_load_lds(
      (const __attribute__((address_space(1))) void*)gptr,
      (__attribute__((address_space(3))) void*)lptr,
      16, 0, 0);
}

__device__ static inline unsigned short f2bf(float x) {
  __hip_bfloat16 h = __float2bfloat16(x);
  return *reinterpret_cast<unsigned short*>(&h);
}

// ---------------- prep: x (NCHW f32) -> Xp[b*2+cg][h'58][khi16][w'64][klo8] bf16
__global__ void k_xprep(const float* __restrict__ x, __hip_bfloat16* __restrict__ Xp) {
  const int t = blockIdx.x * 256 + threadIdx.x;
  const int wq  = t & 63;
  const int khi = (t >> 6) & 15;
  const int t2  = t >> 10;                               // bc*58 + hp
  const int hp  = t2 % 58;
  const int bc  = t2 / 58;
  const int b   = bc >> 1;
  const int cin0 = ((bc & 1) << 7) + (khi << 3);
  const int h = hp - 1, w = wq - 1;
  unsigned short v[8];
  if ((unsigned)h < 56u && (unsigned)w < 56u) {
    const float* xp = x + ((size_t)(b * 256 + cin0) * 56 + h) * 56 + w;
#pragma unroll
    for (int j = 0; j < 8; ++j) v[j] = f2bf(xp[(size_t)j * 3136]);
  } else {
#pragma unroll
    for (int j = 0; j < 8; ++j) v[j] = 0;
  }
  uint4 pk;
  pk.x = (unsigned)v[0] | ((unsigned)v[1] << 16);
  pk.y = (unsigned)v[2] | ((unsigned)v[3] << 16);
  pk.z = (unsigned)v[4] | ((unsigned)v[5] << 16);
  pk.w = (unsigned)v[6] | ((unsigned)v[7] << 16);
  *(uint4*)(Xp + (size_t)t * 8) = pk;
}

// ---------------- prep: binary_w -> Wp[tap9][cg2][cmblk4][cmh2][khi16][cml64][klo8]
__global__ void k_wprep(const float* __restrict__ bw, __hip_bfloat16* __restrict__ Wp) {
  const int idx = blockIdx.x * 256 + threadIdx.x;        // < 1,179,648 exact
  const int klo = idx & 7;
  const int cml = (idx >> 3) & 63;
  const int khi = (idx >> 9) & 15;
  const int cmh = (idx >> 13) & 1;
  const int rest = idx >> 14;                            // (tap*2+cg)*4 + cmblk
  const int cmblk = rest & 3;
  const int tcg = rest >> 2;
  const int cg  = tcg & 1;
  const int tap = tcg >> 1;
  const int kh = tap / 3, kw = tap - kh * 3;
  const int cm  = (cmblk << 7) + (cmh << 6) + cml;
  const int cin = (cg << 7) + (khi << 3) + klo;
  Wp[idx] = __float2bfloat16(bw[((cm * 256 + cin) * 3 + kh) * 3 + kw]);
}

// ---------------- prep: fc_w -> A2[cg4][mtile2][ch2][khi16][cl64][klo8]
__global__ void k_a2prep(const float* __restrict__ fw, __hip_bfloat16* __restrict__ A2) {
  const int idx = blockIdx.x * 256 + threadIdx.x;        // < 131,072 exact
  const int klo = idx & 7;
  const int cl  = (idx >> 3) & 63;
  const int khi = (idx >> 9) & 15;
  const int ch  = (idx >> 13) & 1;
  const int rest = idx >> 14;                            // cg*2 + mtile
  const int mtile = rest & 1;
  const int cg = rest >> 1;
  const int cout = (mtile << 7) + (ch << 6) + cl;
  const int cm   = (cg << 7) + (khi << 3) + klo;
  A2[idx] = __float2bfloat16(fw[cout * 512 + cm]);
}

// ---------------- conv1: 256x256-tile, 32x32x16 MFMA, 1 barrier per K-step --
// Block (mt, nt): cmid [mt*256, mt*256+256), output rows [h0, h0+4), 64 w.
// K = 36 steps of BK=64 (j = 2t+s; t = (tap,cg) chunk, s = khi half).
// LDS 128KiB: buf{0,1} x { A 32KB [wm][cmh@8192][khi8@1024][cml64@16][klo8],
//                          B 32KB [row@8192][khi8@1024][w64@16][klo8] }.
// 8 waves: wm=wv>>2 cmblk within pair, wn=wv&3 output row.
// Per wave: 4 m-tiles (cmh,cml0) x 2 n-tiles (w0) of 32x32, acc[4][2] f32x16.
// Per K-step: 4 ksub of K=16; per ksub 4 A-frags + 2 B-frags (b128), 8 MFMA.

#define SB0 __builtin_amdgcn_sched_barrier(0)
#define MM32(A, B, C) __builtin_amdgcn_mfma_f32_32x32x16_bf16((A), (B), (C), 0, 0, 0)
#define LD8(P) (*(const short8*)(P))

#define MFMAK(A0, A1, A2, A3, B0, B1) do { \
  __builtin_amdgcn_s_setprio(1); \
  acc[0][0] = MM32(A0, B0, acc[0][0]); \
  acc[1][0] = MM32(A1, B0, acc[1][0]); \
  acc[2][0] = MM32(A2, B0, acc[2][0]); \
  acc[3][0] = MM32(A3, B0, acc[3][0]); \
  acc[0][1] = MM32(A0, B1, acc[0][1]); \
  acc[1][1] = MM32(A1, B1, acc[1][1]); \
  acc[2][1] = MM32(A2, B1, acc[2][1]); \
  acc[3][1] = MM32(A3, B1, acc[3][1]); \
  __builtin_amdgcn_s_setprio(0); \
} while (0)

// read one ksub's 6 fragments into a named set (static indices only)
#define READK(KS, A0, A1, A2, A3, B0, B1) do { \
  A0 = LD8(Ab + (KS)*2048 + 0);    A1 = LD8(Ab + (KS)*2048 + 512); \
  A2 = LD8(Ab + (KS)*2048 + 8192); A3 = LD8(Ab + (KS)*2048 + 8704); \
  B0 = LD8(Bb + (KS)*2048 + 0);    B1 = LD8(Bb + (KS)*2048 + 512); \
} while (0)

__global__ __launch_bounds__(512, 2) void k_conv1(
    const __hip_bfloat16* __restrict__ Xp, const __hip_bfloat16* __restrict__ Wp,
    __hip_bfloat16* __restrict__ Y) {
  __shared__ short8 lds_raw[8192];                       // 128 KiB
  char* lds = (char*)lds_raw;
  const int tid  = threadIdx.x;
  const int lane = tid & 63;
  const int wv   = tid >> 6;                             // 0..7
  const int wm   = wv >> 2;                              // 0..1 (cmblk within pair)
  const int wn   = wv & 3;                               // 0..3 (output row)
  const int l31  = lane & 31;
  const int khB  = lane >> 5;
  const int id   = blockIdx.x;
  const int xcd  = id & 7;
  const int seq  = id >> 3;                              // 0..111
  const int mt   = seq & 1;
  const int nt   = xcd * 56 + (seq >> 1);                // 0..447
  const int b    = nt / 14;
  const int h0   = (nt % 14) * 4;

  const char* WpB = (const char*)Wp;
  const char* XpB = (const char*)Xp;

  // per-thread staging offset: (wv&3) slices of 2KB, lane*16 within
  const int thrA = ((wv & 3) << 11) + lane * 16;
  // fragment read bases (32x32x16: row = l&31, k-half = l>>5)
  const int aRd = wm * 16384 + khB * 1024 + l31 * 16;    // + ksub*2048 + {0,512,8192,8704}
  const int bRd = wn * 8192  + khB * 1024 + l31 * 16;    // + ksub*2048 + {0,512}

  floatx16 acc[4][2];
#pragma unroll
  for (int i = 0; i < 4; i++)
#pragma unroll
    for (int j = 0; j < 2; j++)
#pragma unroll
      for (int e = 0; e < 16; e++) acc[i][j][e] = 0.f;

  // ---- prologue: stage K-step 0 (t=0: tap0,cg0 / s=0) into buf0
  {
    const char* gA = WpB + (size_t)(2 * mt + wm) * 32768 + thrA;
    const char* gB = XpB + ((size_t)(b * 2) * 58 + h0 + wm) * 16384 + thrA;
    char* sA = lds + wm * 16384 + thrA;
    char* sB = lds + 32768 + wm * 8192 + thrA;
    async16(gA, sA);                 async16(gA + 1024, sA + 1024);                  // A cmh0
    async16(gB, sB);                 async16(gB + 1024, sB + 1024);                  // B rows 0-1
    async16(gB + 32768, sB + 16384); async16(gB + 32768 + 1024, sB + 16384 + 1024); // B rows 2-3
    async16(gA + 16384, sA + 8192);  async16(gA + 16384 + 1024, sA + 8192 + 1024);  // A cmh1
    SB0;
    asm volatile("s_waitcnt vmcnt(0)" ::: "memory");
    __builtin_amdgcn_s_barrier();
    SB0;
  }

  // one K-step: stage next step into buf[BUF^1] (all 8 loads up front),
  // compute buf[BUF] as 4 ksubs with 2-deep fragment pipeline,
  // single vmcnt(0)+barrier at end.
  auto STEP = [&](int BUF, const char* gA, const char* gB, bool pred) {
    char* ldsC = lds + BUF * 65536;            // compute buffer
    char* ldsS = lds + (BUF ^ 1) * 65536;      // stage target
    const char* Ab = ldsC + aRd;
    const char* Bb = ldsC + 32768 + bRd;
    char* sA = ldsS + wm * 16384 + thrA;
    char* sB = ldsS + 32768 + wm * 8192 + thrA;
    if (pred) {
      async16(gA, sA);                 async16(gA + 1024, sA + 1024);
      async16(gB, sB);                 async16(gB + 1024, sB + 1024);
      async16(gB + 32768, sB + 16384); async16(gB + 32768 + 1024, sB + 16384 + 1024);
      async16(gA + 16384, sA + 8192);  async16(gA + 16384 + 1024, sA + 8192 + 1024);
    }
    SB0;
    short8 xa0, xa1, xa2, xa3, xb0, xb1;       // set X
    short8 ya0, ya1, ya2, ya3, yb0, yb1;       // set Y
    READK(0, xa0, xa1, xa2, xa3, xb0, xb1);
    READK(1, ya0, ya1, ya2, ya3, yb0, yb1);
    MFMAK(xa0, xa1, xa2, xa3, xb0, xb1);       // ksub0
    SB0;
    READK(2, xa0, xa1, xa2, xa3, xb0, xb1);
    MFMAK(ya0, ya1, ya2, ya3, yb0, yb1);       // ksub1
    SB0;
    READK(3, ya0, ya1, ya2, ya3, yb0, yb1);
    MFMAK(xa0, xa1, xa2, xa3, xb0, xb1);       // ksub2
    SB0;
    MFMAK(ya0, ya1, ya2, ya3, yb0, yb1);       // ksub3
    SB0;
    asm volatile("s_waitcnt vmcnt(0)" ::: "memory");
    __builtin_amdgcn_s_barrier();
    SB0;
  };

  for (int j = 0; j < 36; ++j) {
    const int jn   = j + 1;
    const int tn   = jn >> 1;                  // next step's (tap,cg) chunk
    const int sn   = jn & 1;                   // next step's khi half
    const int cgn  = tn & 1;
    const int tapn = tn >> 1;
    const int khn = tapn / 3, kwn = tapn - khn * 3;
    const char* gA = WpB + (size_t)(tn * 4 + 2 * mt + wm) * 32768 + sn * 8192 + thrA;
    const char* gB = XpB + ((size_t)(b * 2 + cgn) * 58 + h0 + khn + wm) * 16384
                     + kwn * 16 + sn * 8192 + thrA;
    STEP(j & 1, gA, gB, j < 35);
  }

  // ---- epilogue: relu -> bf16 -> Y[ntile][cmblk][r2][khi16][w64][klo8]
  // 32x32 C/D: col = l&31, row = (r&3) + 8*(r>>2) + 4*khB (r = 4q+jj)
  // cm_local = cmh*64 + cml0 + row -> khi = cmh*8+(cml0>>3)+q, klo0 = 4*khB.
  const int cmblk = mt * 2 + wm;
  const int ntile = nt * 2 + (wn >> 1);
  const int r2    = wn & 1;
  const size_t ybase = (((size_t)ntile * 4 + cmblk) * 2 + r2) * 8192;
#pragma unroll
  for (int mi = 0; mi < 4; ++mi) {
    const int cmh  = mi >> 1;
    const int cml3 = (mi & 1) * 4;                       // cml0 >> 3
#pragma unroll
    for (int ni = 0; ni < 2; ++ni) {
      const int w = ni * 32 + l31;
      floatx16 f = acc[mi][ni];
#pragma unroll
      for (int q = 0; q < 4; ++q) {
        const int khi  = cmh * 8 + cml3 + q;
        const int klo0 = khB * 4;
        unsigned lo = (unsigned)f2bf(fmaxf(f[4*q+0], 0.f)) | ((unsigned)f2bf(fmaxf(f[4*q+1], 0.f)) << 16);
        unsigned hi = (unsigned)f2bf(fmaxf(f[4*q+2], 0.f)) | ((unsigned)f2bf(fmaxf(f[4*q+3], 0.f)) << 16);
        uint2 pk = make_uint2(lo, hi);
        *(uint2*)((char*)Y + (ybase + (size_t)khi * 512 + w * 8 + klo0) * 2) = pk;
      }
    }
  }
}

// ---------------- conv2: out = fc_w * Y + b, mask w<56, store NCHW f32
__global__ __launch_bounds__(256, 2) void k_conv2(
    const __hip_bfloat16* __restrict__ Y, const __hip_bfloat16* __restrict__ A2,
    const float* __restrict__ fcb, float* __restrict__ out) {
  __shared__ short8 lds_raw[4096];
  char* lds = (char*)lds_raw;
  const int tid  = threadIdx.x;
  const int lane = tid & 63;
  const int wv   = tid >> 6;
  const int wm   = wv >> 1, wn = wv & 1;
  const int l15  = lane & 15;
  const int quad = lane >> 4;
  const int id   = blockIdx.x;
  const int xcd  = id & 7;
  const int seq  = id >> 3;                              // 0..223
  const int mtile = seq & 1;
  const int rp    = xcd * 112 + (seq >> 1);              // 0..895

  floatx4 acc[4][4];
#pragma unroll
  for (int i = 0; i < 4; i++)
#pragma unroll
    for (int j = 0; j < 4; j++) acc[i][j] = (floatx4){0.f, 0.f, 0.f, 0.f};

  for (int cg = 0; cg < 4; ++cg) {
    const size_t a_base = (size_t)(cg * 2 + mtile) * 16384;
    const size_t b_base = (size_t)(rp * 4 + cg) * 16384;
    __syncthreads();
    const char* gA = (const char*)(A2 + a_base) + wv * 8192 + lane * 16;
    const char* gB = (const char*)(Y + b_base) + wv * 8192 + lane * 16;
    char* lA = lds + wv * 8192;
    char* lB = lds + 32768 + wv * 8192;
#pragma unroll
    for (int c = 0; c < 8; ++c) {
      async16(gA + c * 1024, lA + c * 1024);
      async16(gB + c * 1024, lB + c * 1024);
    }
    __syncthreads();
#pragma unroll
    for (int kk = 0; kk < 4; ++kk) {
      short8 af[4], bf[4];
#pragma unroll
      for (int mi = 0; mi < 4; ++mi) {
        const int m = wm * 64 + mi * 16 + l15;
        af[mi] = *(const short8*)(lds + ((m >> 6) * 16 + kk * 4 + quad) * 1024 + (m & 63) * 16);
      }
#pragma unroll
      for (int ni = 0; ni < 4; ++ni) {
        const int n = wn * 64 + ni * 16 + l15;
        bf[ni] = *(const short8*)(lds + 32768 + ((n >> 6) * 16 + kk * 4 + quad) * 1024 + (n & 63) * 16);
      }
#pragma unroll
      for (int mi = 0; mi < 4; ++mi)
#pragma unroll
        for (int ni = 0; ni < 4; ++ni)
          acc[mi][ni] = __builtin_amdgcn_mfma_f32_16x16x32_bf16(af[mi], bf[ni], acc[mi][ni], 0, 0, 0);
    }
  }

  const int b   = rp / NT_PER_B;
  const int nb0 = (rp % NT_PER_B) * 128;
#pragma unroll
  for (int mi = 0; mi < 4; ++mi) {
    const int co = mtile * 128 + wm * 64 + mi * 16 + quad * 4;  // + reg r
#pragma unroll
    for (int ni = 0; ni < 4; ++ni) {
      const int n = wn * 64 + ni * 16 + l15;
      const int w = n & 63;
      if (w < 56) {
        const int nb = nb0 + n;
        const int h  = nb >> 6;
        floatx4 f = acc[mi][ni];
        const size_t base = (size_t)(b * 256 + co) * 3136 + h * 56 + w;
#pragma unroll
        for (int r = 0; r < 4; ++r)
          out[base + (size_t)r * 3136] = f[r] + fcb[co + r];
      }
    }
  }
}

extern "C" void kernel_launch(void* const* d_in, const int* in_sizes, int n_in,
                              void* d_out, int out_size, void* d_ws, size_t ws_size,
                              hipStream_t stream) {
  const float* x  = (const float*)d_in[0];
  const float* bw = (const float*)d_in[1];
  const float* fw = (const float*)d_in[2];
  const float* fb = (const float*)d_in[3];
  float* out = (float*)d_out;
  char* ws = (char*)d_ws;

  __hip_bfloat16* Wp = (__hip_bfloat16*)(ws + OFF_WP);
  __hip_bfloat16* A2 = (__hip_bfloat16*)(ws + OFF_A2);
  __hip_bfloat16* Xp = (__hip_bfloat16*)(ws + OFF_XP);
  __hip_bfloat16* Y  = (__hip_bfloat16*)(ws + OFF_Y);

  k_wprep<<<dim3(4608), dim3(256), 0, stream>>>(bw, Wp);
  k_a2prep<<<dim3(512), dim3(256), 0, stream>>>(fw, A2);
  k_xprep<<<dim3(14848), dim3(256), 0, stream>>>(x, Xp);
  k_conv1<<<dim3(896), dim3(512), 0, stream>>>(Xp, Wp, Y);
  k_conv2<<<dim3(1792), dim3(256), 0, stream>>>(Y, A2, fb, out);
}

// Round 4
// 464.222 us; speedup vs baseline: 1.0864x; 1.0864x over previous
//
#include <hip/hip_runtime.h>
#include <hip/hip_bf16.h>
#include <stdint.h>

// ---------------------------------------------------------------------------
// LBConv: y = fc(relu(conv3x3_ternary(x))) + b
//   x        : [32][256][56][56] f32
//   binary_w : [512][256][3][3]  f32 (ternary)
//   fc_w     : [256][512]        f32
//   fc_b     : [256]             f32
//   out      : [32][256][56][56] f32
//
// R6 changes vs R5 (504us total; conv1 280us @ MfmaUtil 43.5%):
//  - Diagnosis across R2-R5: every 1-block-per-CU conv1 (42-46%) loses to
//    2-blocks-per-CU R2 (48%) -- the vmcnt(0)+barrier drain needs a second
//    resident block to fill it (m114 implicit overlap). 128KiB LDS was the
//    real regression cause, not barrier count (R4 null) nor MFMA shape (R5).
//  - New conv1: 256x128 tile, BK=32, 4 waves of 128x64 each (0.0458 B/MAC
//    LDS-read ratio, same per-wave shape as m201), double-buffered LDS
//    2x24KiB = 48KiB/block -> 2 blocks/CU co-resident. One vmcnt(0)+barrier
//    per K-step, 72 steps; drains hidden by the sibling block.
//  - Grid 1792 = 896 ntiles x 2 mt at 2 blocks/CU = exactly 7.0 rounds
//    (kills the 3.5-round tail of R3-R5).
//  - 16x16x32 MFMA (R2's verified fragment/C-D path). conv2/preps unchanged.
// ---------------------------------------------------------------------------

typedef __attribute__((ext_vector_type(8))) short short8;
typedef __attribute__((ext_vector_type(4))) float floatx4;

#define ROWE 8192            // elems per padded row per (b,cg): 16*64*8
#define NT_PER_B 28          // ntiles (128-col units) per batch image

// workspace byte offsets
#define OFF_WP  0            // 9*2*512*128*2        = 2,359,296
#define OFF_A2  2359296      // 4*2*128*128*2        =   262,144
#define OFF_XP  2621440      // 64*58*8192*2         = 60,817,408
#define OFF_Y   63439872     // 896*4*16384*2        = 117,440,512
// total required ws: 180,880,384 bytes (~173 MB)

__device__ static inline void async16(const void* gptr, void* lptr) {
  __builtin_amdgcn_global_load_lds(
      (const __attribute__((address_space(1))) void*)gptr,
      (__attribute__((address_space(3))) void*)lptr,
      16, 0, 0);
}

__device__ static inline unsigned short f2bf(float x) {
  __hip_bfloat16 h = __float2bfloat16(x);
  return *reinterpret_cast<unsigned short*>(&h);
}

// ---------------- prep: x (NCHW f32) -> Xp[b*2+cg][h'58][khi16][w'64][klo8] bf16
__global__ void k_xprep(const float* __restrict__ x, __hip_bfloat16* __restrict__ Xp) {
  const int t = blockIdx.x * 256 + threadIdx.x;
  const int wq  = t & 63;
  const int khi = (t >> 6) & 15;
  const int t2  = t >> 10;                               // bc*58 + hp
  const int hp  = t2 % 58;
  const int bc  = t2 / 58;
  const int b   = bc >> 1;
  const int cin0 = ((bc & 1) << 7) + (khi << 3);
  const int h = hp - 1, w = wq - 1;
  unsigned short v[8];
  if ((unsigned)h < 56u && (unsigned)w < 56u) {
    const float* xp = x + ((size_t)(b * 256 + cin0) * 56 + h) * 56 + w;
#pragma unroll
    for (int j = 0; j < 8; ++j) v[j] = f2bf(xp[(size_t)j * 3136]);
  } else {
#pragma unroll
    for (int j = 0; j < 8; ++j) v[j] = 0;
  }
  uint4 pk;
  pk.x = (unsigned)v[0] | ((unsigned)v[1] << 16);
  pk.y = (unsigned)v[2] | ((unsigned)v[3] << 16);
  pk.z = (unsigned)v[4] | ((unsigned)v[5] << 16);
  pk.w = (unsigned)v[6] | ((unsigned)v[7] << 16);
  *(uint4*)(Xp + (size_t)t * 8) = pk;
}

// ---------------- prep: binary_w -> Wp[tap9][cg2][cmblk4][cmh2][khi16][cml64][klo8]
__global__ void k_wprep(const float* __restrict__ bw, __hip_bfloat16* __restrict__ Wp) {
  const int idx = blockIdx.x * 256 + threadIdx.x;        // < 1,179,648 exact
  const int klo = idx & 7;
  const int cml = (idx >> 3) & 63;
  const int khi = (idx >> 9) & 15;
  const int cmh = (idx >> 13) & 1;
  const int rest = idx >> 14;                            // (tap*2+cg)*4 + cmblk
  const int cmblk = rest & 3;
  const int tcg = rest >> 2;
  const int cg  = tcg & 1;
  const int tap = tcg >> 1;
  const int kh = tap / 3, kw = tap - kh * 3;
  const int cm  = (cmblk << 7) + (cmh << 6) + cml;
  const int cin = (cg << 7) + (khi << 3) + klo;
  Wp[idx] = __float2bfloat16(bw[((cm * 256 + cin) * 3 + kh) * 3 + kw]);
}

// ---------------- prep: fc_w -> A2[cg4][mtile2][ch2][khi16][cl64][klo8]
__global__ void k_a2prep(const float* __restrict__ fw, __hip_bfloat16* __restrict__ A2) {
  const int idx = blockIdx.x * 256 + threadIdx.x;        // < 131,072 exact
  const int klo = idx & 7;
  const int cl  = (idx >> 3) & 63;
  const int khi = (idx >> 9) & 15;
  const int ch  = (idx >> 13) & 1;
  const int rest = idx >> 14;                            // cg*2 + mtile
  const int mtile = rest & 1;
  const int cg = rest >> 1;
  const int cout = (mtile << 7) + (ch << 6) + cl;
  const int cm   = (cg << 7) + (khi << 3) + klo;
  A2[idx] = __float2bfloat16(fw[cout * 512 + cm]);
}

// ---------------- conv1: 256x128 tile, BK=32, dbuf 48KiB, 2 blocks/CU -------
// Block (mt, ntile): cmid [mt*256, mt*256+256), 128 n (= 2 rows x 64 w).
// K = 72 steps of BK=32 (j: t = j>>2 picks (tap,cg), sp = j&3 picks khi quad).
// LDS 48KiB: buf{0,1} x 24KiB { A 16KB [cb2][cmh2][khi4][cml64][klo8],
//                               B  8KB [row2][khi4][w64][klo8] }.
// 4 waves 2x2: wm picks cb (cmblk within pair), wn picks output row.
// Per wave per step: 8 A-frags + 4 B-frags (b128), 32 MFMA 16x16x32.
// Staging: 6 async16/thread (4 A pieces + 2 B rows, 4KB sweeps).

#define SB0 __builtin_amdgcn_sched_barrier(0)
#define MM(A, B, C) __builtin_amdgcn_mfma_f32_16x16x32_bf16((A), (B), (C), 0, 0, 0)
#define LD8(P) (*(const short8*)(P))

__global__ __launch_bounds__(256, 2) void k_conv1(
    const __hip_bfloat16* __restrict__ Xp, const __hip_bfloat16* __restrict__ Wp,
    __hip_bfloat16* __restrict__ Y) {
  __shared__ short8 lds_raw[3072];                       // 48 KiB
  char* lds = (char*)lds_raw;
  const int tid  = threadIdx.x;
  const int lane = tid & 63;
  const int wv   = tid >> 6;                             // 0..3
  const int wm   = wv >> 1;                              // 0..1 (cb = cmblk in pair)
  const int wn   = wv & 1;                               // 0..1 (output row)
  const int l15  = lane & 15;
  const int quad = lane >> 4;
  const int id   = blockIdx.x;
  const int xcd  = id & 7;
  const int seq  = id >> 3;                              // 0..223
  const int mt   = seq & 1;
  const int ntile = xcd * 112 + (seq >> 1);              // 0..895
  const int b    = ntile / NT_PER_B;
  const int h0   = (ntile % NT_PER_B) * 2;

  const char* WpB = (const char*)Wp;
  const char* XpB = (const char*)Xp;
  const int thr16 = tid * 16;

  // fragment read bases (16x16x32: col/row = l15, k = quad*8+klo)
  const int aRd = wm * 8192 + quad * 1024 + l15 * 16;    // + (mi>>2)*4096 + (mi&3)*256
  const int bRd = 16384 + wn * 4096 + quad * 1024 + l15 * 16;  // + ni*256

  floatx4 acc[8][4];
#pragma unroll
  for (int i = 0; i < 8; i++)
#pragma unroll
    for (int j = 0; j < 4; j++) acc[i][j] = (floatx4){0.f, 0.f, 0.f, 0.f};

  // stage K-step (t, sp) into sbase: A 4 pieces of 4KB (cb,cmh), B 2 rows of 4KB
  auto STAGE = [&](char* sbase, int t, int sp) {
    const int cg  = t & 1;
    const int tap = t >> 1;
    const int kh = tap / 3, kw = tap - kh * 3;
#pragma unroll
    for (int cb = 0; cb < 2; ++cb)
#pragma unroll
      for (int cmh = 0; cmh < 2; ++cmh)
        async16(WpB + ((size_t)((t * 4 + mt * 2 + cb) * 2 + cmh)) * 16384
                    + sp * 4096 + thr16,
                sbase + (cb * 2 + cmh) * 4096 + thr16);
#pragma unroll
    for (int r = 0; r < 2; ++r)
      async16(XpB + ((size_t)((b * 2 + cg) * 58 + h0 + kh + r)) * 16384
                  + sp * 4096 + kw * 16 + thr16,
              sbase + 16384 + r * 4096 + thr16);
  };

  // ---- prologue: stage K-step 0 into buf0
  STAGE(lds, 0, 0);
  SB0;
  asm volatile("s_waitcnt vmcnt(0)" ::: "memory");
  __builtin_amdgcn_s_barrier();
  SB0;

  for (int j = 0; j < 72; ++j) {
    char* ldsC = lds + (j & 1) * 24576;          // compute buffer
    char* ldsS = lds + ((j & 1) ^ 1) * 24576;    // stage target
    if (j < 71) STAGE(ldsS, (j + 1) >> 2, (j + 1) & 3);
    SB0;
    const char* Ab = ldsC + aRd;
    const char* Bb = ldsC + bRd;
    short8 a0, a1, a2, a3, a4, a5, a6, a7, b0, b1, b2, b3;
    a0 = LD8(Ab + 0);    a1 = LD8(Ab + 256);  a2 = LD8(Ab + 512);  a3 = LD8(Ab + 768);
    a4 = LD8(Ab + 4096); a5 = LD8(Ab + 4352); a6 = LD8(Ab + 4608); a7 = LD8(Ab + 4864);
    b0 = LD8(Bb + 0);    b1 = LD8(Bb + 256);  b2 = LD8(Bb + 512);  b3 = LD8(Bb + 768);
    __builtin_amdgcn_s_setprio(1);
    acc[0][0] = MM(a0, b0, acc[0][0]);  acc[0][1] = MM(a0, b1, acc[0][1]);
    acc[0][2] = MM(a0, b2, acc[0][2]);  acc[0][3] = MM(a0, b3, acc[0][3]);
    acc[1][0] = MM(a1, b0, acc[1][0]);  acc[1][1] = MM(a1, b1, acc[1][1]);
    acc[1][2] = MM(a1, b2, acc[1][2]);  acc[1][3] = MM(a1, b3, acc[1][3]);
    acc[2][0] = MM(a2, b0, acc[2][0]);  acc[2][1] = MM(a2, b1, acc[2][1]);
    acc[2][2] = MM(a2, b2, acc[2][2]);  acc[2][3] = MM(a2, b3, acc[2][3]);
    acc[3][0] = MM(a3, b0, acc[3][0]);  acc[3][1] = MM(a3, b1, acc[3][1]);
    acc[3][2] = MM(a3, b2, acc[3][2]);  acc[3][3] = MM(a3, b3, acc[3][3]);
    acc[4][0] = MM(a4, b0, acc[4][0]);  acc[4][1] = MM(a4, b1, acc[4][1]);
    acc[4][2] = MM(a4, b2, acc[4][2]);  acc[4][3] = MM(a4, b3, acc[4][3]);
    acc[5][0] = MM(a5, b0, acc[5][0]);  acc[5][1] = MM(a5, b1, acc[5][1]);
    acc[5][2] = MM(a5, b2, acc[5][2]);  acc[5][3] = MM(a5, b3, acc[5][3]);
    acc[6][0] = MM(a6, b0, acc[6][0]);  acc[6][1] = MM(a6, b1, acc[6][1]);
    acc[6][2] = MM(a6, b2, acc[6][2]);  acc[6][3] = MM(a6, b3, acc[6][3]);
    acc[7][0] = MM(a7, b0, acc[7][0]);  acc[7][1] = MM(a7, b1, acc[7][1]);
    acc[7][2] = MM(a7, b2, acc[7][2]);  acc[7][3] = MM(a7, b3, acc[7][3]);
    __builtin_amdgcn_s_setprio(0);
    SB0;
    asm volatile("s_waitcnt vmcnt(0)" ::: "memory");
    __builtin_amdgcn_s_barrier();
    SB0;
  }

  // ---- epilogue: relu -> bf16 -> Y[ntile][cmblk4][r2][khi16][w64][klo8]
  const int cmblk = mt * 2 + wm;
  const size_t ybase = ((size_t)ntile * 4 + cmblk) * 16384;
#pragma unroll
  for (int mi = 0; mi < 8; ++mi) {
    const int cml  = mi * 16 + quad * 4;                 // + reg r (0..3)
    const int khi  = cml >> 3;
    const int klo0 = cml & 7;                            // 0 or 4
#pragma unroll
    for (int ni = 0; ni < 4; ++ni) {
      const int w = ni * 16 + l15;
      floatx4 f = acc[mi][ni];
      unsigned lo = (unsigned)f2bf(fmaxf(f[0], 0.f)) | ((unsigned)f2bf(fmaxf(f[1], 0.f)) << 16);
      unsigned hi = (unsigned)f2bf(fmaxf(f[2], 0.f)) | ((unsigned)f2bf(fmaxf(f[3], 0.f)) << 16);
      uint2 pk = make_uint2(lo, hi);
      *(uint2*)((char*)Y + (ybase + (size_t)wn * 8192 + khi * 512 + w * 8 + klo0) * 2) = pk;
    }
  }
}

// ---------------- conv2: out = fc_w * Y + b, mask w<56, store NCHW f32
__global__ __launch_bounds__(256, 2) void k_conv2(
    const __hip_bfloat16* __restrict__ Y, const __hip_bfloat16* __restrict__ A2,
    const float* __restrict__ fcb, float* __restrict__ out) {
  __shared__ short8 lds_raw[4096];
  char* lds = (char*)lds_raw;
  const int tid  = threadIdx.x;
  const int lane = tid & 63;
  const int wv   = tid >> 6;
  const int wm   = wv >> 1, wn = wv & 1;
  const int l15  = lane & 15;
  const int quad = lane >> 4;
  const int id   = blockIdx.x;
  const int xcd  = id & 7;
  const int seq  = id >> 3;                              // 0..223
  const int mtile = seq & 1;
  const int rp    = xcd * 112 + (seq >> 1);              // 0..895

  floatx4 acc[4][4];
#pragma unroll
  for (int i = 0; i < 4; i++)
#pragma unroll
    for (int j = 0; j < 4; j++) acc[i][j] = (floatx4){0.f, 0.f, 0.f, 0.f};

  for (int cg = 0; cg < 4; ++cg) {
    const size_t a_base = (size_t)(cg * 2 + mtile) * 16384;
    const size_t b_base = (size_t)(rp * 4 + cg) * 16384;
    __syncthreads();
    const char* gA = (const char*)(A2 + a_base) + wv * 8192 + lane * 16;
    const char* gB = (const char*)(Y + b_base) + wv * 8192 + lane * 16;
    char* lA = lds + wv * 8192;
    char* lB = lds + 32768 + wv * 8192;
#pragma unroll
    for (int c = 0; c < 8; ++c) {
      async16(gA + c * 1024, lA + c * 1024);
      async16(gB + c * 1024, lB + c * 1024);
    }
    __syncthreads();
#pragma unroll
    for (int kk = 0; kk < 4; ++kk) {
      short8 af[4], bf[4];
#pragma unroll
      for (int mi = 0; mi < 4; ++mi) {
        const int m = wm * 64 + mi * 16 + l15;
        af[mi] = *(const short8*)(lds + ((m >> 6) * 16 + kk * 4 + quad) * 1024 + (m & 63) * 16);
      }
#pragma unroll
      for (int ni = 0; ni < 4; ++ni) {
        const int n = wn * 64 + ni * 16 + l15;
        bf[ni] = *(const short8*)(lds + 32768 + ((n >> 6) * 16 + kk * 4 + quad) * 1024 + (n & 63) * 16);
      }
#pragma unroll
      for (int mi = 0; mi < 4; ++mi)
#pragma unroll
        for (int ni = 0; ni < 4; ++ni)
          acc[mi][ni] = __builtin_amdgcn_mfma_f32_16x16x32_bf16(af[mi], bf[ni], acc[mi][ni], 0, 0, 0);
    }
  }

  const int b   = rp / NT_PER_B;
  const int nb0 = (rp % NT_PER_B) * 128;
#pragma unroll
  for (int mi = 0; mi < 4; ++mi) {
    const int co = mtile * 128 + wm * 64 + mi * 16 + quad * 4;  // + reg r
#pragma unroll
    for (int ni = 0; ni < 4; ++ni) {
      const int n = wn * 64 + ni * 16 + l15;
      const int w = n & 63;
      if (w < 56) {
        const int nb = nb0 + n;
        const int h  = nb >> 6;
        floatx4 f = acc[mi][ni];
        const size_t base = (size_t)(b * 256 + co) * 3136 + h * 56 + w;
#pragma unroll
        for (int r = 0; r < 4; ++r)
          out[base + (size_t)r * 3136] = f[r] + fcb[co + r];
      }
    }
  }
}

extern "C" void kernel_launch(void* const* d_in, const int* in_sizes, int n_in,
                              void* d_out, int out_size, void* d_ws, size_t ws_size,
                              hipStream_t stream) {
  const float* x  = (const float*)d_in[0];
  const float* bw = (const float*)d_in[1];
  const float* fw = (const float*)d_in[2];
  const float* fb = (const float*)d_in[3];
  float* out = (float*)d_out;
  char* ws = (char*)d_ws;

  __hip_bfloat16* Wp = (__hip_bfloat16*)(ws + OFF_WP);
  __hip_bfloat16* A2 = (__hip_bfloat16*)(ws + OFF_A2);
  __hip_bfloat16* Xp = (__hip_bfloat16*)(ws + OFF_XP);
  __hip_bfloat16* Y  = (__hip_bfloat16*)(ws + OFF_Y);

  k_wprep<<<dim3(4608), dim3(256), 0, stream>>>(bw, Wp);
  k_a2prep<<<dim3(512), dim3(256), 0, stream>>>(fw, A2);
  k_xprep<<<dim3(14848), dim3(256), 0, stream>>>(x, Xp);
  k_conv1<<<dim3(1792), dim3(256), 0, stream>>>(Xp, Wp, Y);
  k_conv2<<<dim3(1792), dim3(256), 0, stream>>>(Y, A2, fb, out);
}

// Round 5
// 451.852 us; speedup vs baseline: 1.1161x; 1.0274x over previous
//
#include <hip/hip_runtime.h>
#include <hip/hip_bf16.h>
#include <stdint.h>

// ---------------------------------------------------------------------------
// LBConv: y = fc(relu(conv3x3_ternary(x))) + b
//   x        : [32][256][56][56] f32
//   binary_w : [512][256][3][3]  f32 (ternary)
//   fc_w     : [256][512]        f32
//   fc_b     : [256]             f32
//   out      : [32][256][56][56] f32
//
// R7 changes vs R6 (464us total; conv1 229us @ 52% MfmaUtil):
//  - conv1 kept as R6 (256x128/BK=32/48KiB dbuf/2 blocks/CU) -- confirmed win.
//  - conv2 rewritten to the same structure: BK=64, 8 chunks, double-buffered
//    2x32KiB = 64KiB LDS (still 2 blocks/CU), stage chunk j+1 while computing
//    chunk j, ONE vmcnt(0)+s_barrier per chunk (was: 4 chunks, single-buffer,
//    full __syncthreads drain each -- latency-serialized, ~5x off its 26us
//    HBM floor). Source layouts unchanged: khi-half sp of a cg chunk is at
//    ch*16384 + sp*8192 (A2) and r*16384 + sp*8192 (Y). Store path identical.
// ---------------------------------------------------------------------------

typedef __attribute__((ext_vector_type(8))) short short8;
typedef __attribute__((ext_vector_type(4))) float floatx4;

#define ROWE 8192            // elems per padded row per (b,cg): 16*64*8
#define NT_PER_B 28          // ntiles (128-col units) per batch image

// workspace byte offsets
#define OFF_WP  0            // 9*2*512*128*2        = 2,359,296
#define OFF_A2  2359296      // 4*2*128*128*2        =   262,144
#define OFF_XP  2621440      // 64*58*8192*2         = 60,817,408
#define OFF_Y   63439872     // 896*4*16384*2        = 117,440,512
// total required ws: 180,880,384 bytes (~173 MB)

__device__ static inline void async16(const void* gptr, void* lptr) {
  __builtin_amdgcn_global_load_lds(
      (const __attribute__((address_space(1))) void*)gptr,
      (__attribute__((address_space(3))) void*)lptr,
      16, 0, 0);
}

__device__ static inline unsigned short f2bf(float x) {
  __hip_bfloat16 h = __float2bfloat16(x);
  return *reinterpret_cast<unsigned short*>(&h);
}

// ---------------- prep: x (NCHW f32) -> Xp[b*2+cg][h'58][khi16][w'64][klo8] bf16
__global__ void k_xprep(const float* __restrict__ x, __hip_bfloat16* __restrict__ Xp) {
  const int t = blockIdx.x * 256 + threadIdx.x;
  const int wq  = t & 63;
  const int khi = (t >> 6) & 15;
  const int t2  = t >> 10;                               // bc*58 + hp
  const int hp  = t2 % 58;
  const int bc  = t2 / 58;
  const int b   = bc >> 1;
  const int cin0 = ((bc & 1) << 7) + (khi << 3);
  const int h = hp - 1, w = wq - 1;
  unsigned short v[8];
  if ((unsigned)h < 56u && (unsigned)w < 56u) {
    const float* xp = x + ((size_t)(b * 256 + cin0) * 56 + h) * 56 + w;
#pragma unroll
    for (int j = 0; j < 8; ++j) v[j] = f2bf(xp[(size_t)j * 3136]);
  } else {
#pragma unroll
    for (int j = 0; j < 8; ++j) v[j] = 0;
  }
  uint4 pk;
  pk.x = (unsigned)v[0] | ((unsigned)v[1] << 16);
  pk.y = (unsigned)v[2] | ((unsigned)v[3] << 16);
  pk.z = (unsigned)v[4] | ((unsigned)v[5] << 16);
  pk.w = (unsigned)v[6] | ((unsigned)v[7] << 16);
  *(uint4*)(Xp + (size_t)t * 8) = pk;
}

// ---------------- prep: binary_w -> Wp[tap9][cg2][cmblk4][cmh2][khi16][cml64][klo8]
__global__ void k_wprep(const float* __restrict__ bw, __hip_bfloat16* __restrict__ Wp) {
  const int idx = blockIdx.x * 256 + threadIdx.x;        // < 1,179,648 exact
  const int klo = idx & 7;
  const int cml = (idx >> 3) & 63;
  const int khi = (idx >> 9) & 15;
  const int cmh = (idx >> 13) & 1;
  const int rest = idx >> 14;                            // (tap*2+cg)*4 + cmblk
  const int cmblk = rest & 3;
  const int tcg = rest >> 2;
  const int cg  = tcg & 1;
  const int tap = tcg >> 1;
  const int kh = tap / 3, kw = tap - kh * 3;
  const int cm  = (cmblk << 7) + (cmh << 6) + cml;
  const int cin = (cg << 7) + (khi << 3) + klo;
  Wp[idx] = __float2bfloat16(bw[((cm * 256 + cin) * 3 + kh) * 3 + kw]);
}

// ---------------- prep: fc_w -> A2[cg4][mtile2][ch2][khi16][cl64][klo8]
__global__ void k_a2prep(const float* __restrict__ fw, __hip_bfloat16* __restrict__ A2) {
  const int idx = blockIdx.x * 256 + threadIdx.x;        // < 131,072 exact
  const int klo = idx & 7;
  const int cl  = (idx >> 3) & 63;
  const int khi = (idx >> 9) & 15;
  const int ch  = (idx >> 13) & 1;
  const int rest = idx >> 14;                            // cg*2 + mtile
  const int mtile = rest & 1;
  const int cg = rest >> 1;
  const int cout = (mtile << 7) + (ch << 6) + cl;
  const int cm   = (cg << 7) + (khi << 3) + klo;
  A2[idx] = __float2bfloat16(fw[cout * 512 + cm]);
}

// ---------------- conv1: 256x128 tile, BK=32, dbuf 48KiB, 2 blocks/CU -------
// (unchanged from R6)

#define SB0 __builtin_amdgcn_sched_barrier(0)
#define MM(A, B, C) __builtin_amdgcn_mfma_f32_16x16x32_bf16((A), (B), (C), 0, 0, 0)
#define LD8(P) (*(const short8*)(P))

__global__ __launch_bounds__(256, 2) void k_conv1(
    const __hip_bfloat16* __restrict__ Xp, const __hip_bfloat16* __restrict__ Wp,
    __hip_bfloat16* __restrict__ Y) {
  __shared__ short8 lds_raw[3072];                       // 48 KiB
  char* lds = (char*)lds_raw;
  const int tid  = threadIdx.x;
  const int lane = tid & 63;
  const int wv   = tid >> 6;                             // 0..3
  const int wm   = wv >> 1;                              // 0..1 (cb = cmblk in pair)
  const int wn   = wv & 1;                               // 0..1 (output row)
  const int l15  = lane & 15;
  const int quad = lane >> 4;
  const int id   = blockIdx.x;
  const int xcd  = id & 7;
  const int seq  = id >> 3;                              // 0..223
  const int mt   = seq & 1;
  const int ntile = xcd * 112 + (seq >> 1);              // 0..895
  const int b    = ntile / NT_PER_B;
  const int h0   = (ntile % NT_PER_B) * 2;

  const char* WpB = (const char*)Wp;
  const char* XpB = (const char*)Xp;
  const int thr16 = tid * 16;

  // fragment read bases (16x16x32: col/row = l15, k = quad*8+klo)
  const int aRd = wm * 8192 + quad * 1024 + l15 * 16;    // + (mi>>2)*4096 + (mi&3)*256
  const int bRd = 16384 + wn * 4096 + quad * 1024 + l15 * 16;  // + ni*256

  floatx4 acc[8][4];
#pragma unroll
  for (int i = 0; i < 8; i++)
#pragma unroll
    for (int j = 0; j < 4; j++) acc[i][j] = (floatx4){0.f, 0.f, 0.f, 0.f};

  // stage K-step (t, sp) into sbase: A 4 pieces of 4KB (cb,cmh), B 2 rows of 4KB
  auto STAGE = [&](char* sbase, int t, int sp) {
    const int cg  = t & 1;
    const int tap = t >> 1;
    const int kh = tap / 3, kw = tap - kh * 3;
#pragma unroll
    for (int cb = 0; cb < 2; ++cb)
#pragma unroll
      for (int cmh = 0; cmh < 2; ++cmh)
        async16(WpB + ((size_t)((t * 4 + mt * 2 + cb) * 2 + cmh)) * 16384
                    + sp * 4096 + thr16,
                sbase + (cb * 2 + cmh) * 4096 + thr16);
#pragma unroll
    for (int r = 0; r < 2; ++r)
      async16(XpB + ((size_t)((b * 2 + cg) * 58 + h0 + kh + r)) * 16384
                  + sp * 4096 + kw * 16 + thr16,
              sbase + 16384 + r * 4096 + thr16);
  };

  // ---- prologue: stage K-step 0 into buf0
  STAGE(lds, 0, 0);
  SB0;
  asm volatile("s_waitcnt vmcnt(0)" ::: "memory");
  __builtin_amdgcn_s_barrier();
  SB0;

  for (int j = 0; j < 72; ++j) {
    char* ldsC = lds + (j & 1) * 24576;          // compute buffer
    char* ldsS = lds + ((j & 1) ^ 1) * 24576;    // stage target
    if (j < 71) STAGE(ldsS, (j + 1) >> 2, (j + 1) & 3);
    SB0;
    const char* Ab = ldsC + aRd;
    const char* Bb = ldsC + bRd;
    short8 a0, a1, a2, a3, a4, a5, a6, a7, b0, b1, b2, b3;
    a0 = LD8(Ab + 0);    a1 = LD8(Ab + 256);  a2 = LD8(Ab + 512);  a3 = LD8(Ab + 768);
    a4 = LD8(Ab + 4096); a5 = LD8(Ab + 4352); a6 = LD8(Ab + 4608); a7 = LD8(Ab + 4864);
    b0 = LD8(Bb + 0);    b1 = LD8(Bb + 256);  b2 = LD8(Bb + 512);  b3 = LD8(Bb + 768);
    __builtin_amdgcn_s_setprio(1);
    acc[0][0] = MM(a0, b0, acc[0][0]);  acc[0][1] = MM(a0, b1, acc[0][1]);
    acc[0][2] = MM(a0, b2, acc[0][2]);  acc[0][3] = MM(a0, b3, acc[0][3]);
    acc[1][0] = MM(a1, b0, acc[1][0]);  acc[1][1] = MM(a1, b1, acc[1][1]);
    acc[1][2] = MM(a1, b2, acc[1][2]);  acc[1][3] = MM(a1, b3, acc[1][3]);
    acc[2][0] = MM(a2, b0, acc[2][0]);  acc[2][1] = MM(a2, b1, acc[2][1]);
    acc[2][2] = MM(a2, b2, acc[2][2]);  acc[2][3] = MM(a2, b3, acc[2][3]);
    acc[3][0] = MM(a3, b0, acc[3][0]);  acc[3][1] = MM(a3, b1, acc[3][1]);
    acc[3][2] = MM(a3, b2, acc[3][2]);  acc[3][3] = MM(a3, b3, acc[3][3]);
    acc[4][0] = MM(a4, b0, acc[4][0]);  acc[4][1] = MM(a4, b1, acc[4][1]);
    acc[4][2] = MM(a4, b2, acc[4][2]);  acc[4][3] = MM(a4, b3, acc[4][3]);
    acc[5][0] = MM(a5, b0, acc[5][0]);  acc[5][1] = MM(a5, b1, acc[5][1]);
    acc[5][2] = MM(a5, b2, acc[5][2]);  acc[5][3] = MM(a5, b3, acc[5][3]);
    acc[6][0] = MM(a6, b0, acc[6][0]);  acc[6][1] = MM(a6, b1, acc[6][1]);
    acc[6][2] = MM(a6, b2, acc[6][2]);  acc[6][3] = MM(a6, b3, acc[6][3]);
    acc[7][0] = MM(a7, b0, acc[7][0]);  acc[7][1] = MM(a7, b1, acc[7][1]);
    acc[7][2] = MM(a7, b2, acc[7][2]);  acc[7][3] = MM(a7, b3, acc[7][3]);
    __builtin_amdgcn_s_setprio(0);
    SB0;
    asm volatile("s_waitcnt vmcnt(0)" ::: "memory");
    __builtin_amdgcn_s_barrier();
    SB0;
  }

  // ---- epilogue: relu -> bf16 -> Y[ntile][cmblk4][r2][khi16][w64][klo8]
  const int cmblk = mt * 2 + wm;
  const size_t ybase = ((size_t)ntile * 4 + cmblk) * 16384;
#pragma unroll
  for (int mi = 0; mi < 8; ++mi) {
    const int cml  = mi * 16 + quad * 4;                 // + reg r (0..3)
    const int khi  = cml >> 3;
    const int klo0 = cml & 7;                            // 0 or 4
#pragma unroll
    for (int ni = 0; ni < 4; ++ni) {
      const int w = ni * 16 + l15;
      floatx4 f = acc[mi][ni];
      unsigned lo = (unsigned)f2bf(fmaxf(f[0], 0.f)) | ((unsigned)f2bf(fmaxf(f[1], 0.f)) << 16);
      unsigned hi = (unsigned)f2bf(fmaxf(f[2], 0.f)) | ((unsigned)f2bf(fmaxf(f[3], 0.f)) << 16);
      uint2 pk = make_uint2(lo, hi);
      *(uint2*)((char*)Y + (ybase + (size_t)wn * 8192 + khi * 512 + w * 8 + klo0) * 2) = pk;
    }
  }
}

// ---------------- conv2: out = fc_w * Y + b -- BK=64, dbuf 64KiB, 2 blk/CU --
// Block (mtile, rp): couts [mtile*128, +128), 128 pixels (= 2 rows x 64 w).
// K = 512 = 8 chunks of 64 (j: cg = j>>1, sp = j&1 khi-half).
// LDS 64KiB: buf{0,1} x 32KiB { A 16KB [ch2][khi8][cl64][klo8],
//                               B 16KB [r2][khi8][w64][klo8] }.
// 4 waves 2x2: wm cout-half, wn pixel-row. Per chunk per wave: 8 A + 8 B
// frags (b128), 32 MFMA 16x16x32. Stage next chunk during compute; one
// vmcnt(0)+s_barrier per chunk; 2 blocks/CU hide the drains.
__global__ __launch_bounds__(256, 2) void k_conv2(
    const __hip_bfloat16* __restrict__ Y, const __hip_bfloat16* __restrict__ A2,
    const float* __restrict__ fcb, float* __restrict__ out) {
  __shared__ short8 lds_raw[4096];                       // 64 KiB
  char* lds = (char*)lds_raw;
  const int tid  = threadIdx.x;
  const int lane = tid & 63;
  const int wv   = tid >> 6;
  const int wm   = wv >> 1, wn = wv & 1;
  const int l15  = lane & 15;
  const int quad = lane >> 4;
  const int id   = blockIdx.x;
  const int xcd  = id & 7;
  const int seq  = id >> 3;                              // 0..223
  const int mtile = seq & 1;
  const int rp    = xcd * 112 + (seq >> 1);              // 0..895

  const char* A2B = (const char*)A2;
  const char* YB  = (const char*)Y;
  const int thr16 = tid * 16;

  // fragment read bases
  const int aRd = wm * 8192 + quad * 1024 + l15 * 16;    // +(mi&1? no) see below
  const int bRd = 16384 + wn * 8192 + quad * 1024 + l15 * 16;

  floatx4 acc[4][4];
#pragma unroll
  for (int i = 0; i < 4; i++)
#pragma unroll
    for (int j = 0; j < 4; j++) acc[i][j] = (floatx4){0.f, 0.f, 0.f, 0.f};

  // stage chunk (cg, sp) into sbase:
  //  A: ch pieces of 8KB from A2[(cg*2+mtile)]: ch*16384 + sp*8192
  //  B: r  pieces of 8KB from Y[(rp*4+cg)]:     r*16384 + sp*8192
  auto STAGE = [&](char* sbase, int cg, int sp) {
    const size_t aOff = (size_t)(cg * 2 + mtile) * 32768 + sp * 8192;
    const size_t bOff = ((size_t)rp * 4 + cg) * 32768 + sp * 8192;
#pragma unroll
    for (int ch = 0; ch < 2; ++ch)
#pragma unroll
      for (int c = 0; c < 2; ++c)
        async16(A2B + aOff + ch * 16384 + c * 4096 + thr16,
                sbase + ch * 8192 + c * 4096 + thr16);
#pragma unroll
    for (int r = 0; r < 2; ++r)
#pragma unroll
      for (int c = 0; c < 2; ++c)
        async16(YB + bOff + r * 16384 + c * 4096 + thr16,
                sbase + 16384 + r * 8192 + c * 4096 + thr16);
  };

  // ---- prologue
  STAGE(lds, 0, 0);
  SB0;
  asm volatile("s_waitcnt vmcnt(0)" ::: "memory");
  __builtin_amdgcn_s_barrier();
  SB0;

  for (int j = 0; j < 8; ++j) {
    char* ldsC = lds + (j & 1) * 32768;
    char* ldsS = lds + ((j & 1) ^ 1) * 32768;
    if (j < 7) STAGE(ldsS, (j + 1) >> 1, (j + 1) & 1);
    SB0;
    const char* Ab = ldsC + aRd;
    const char* Bb = ldsC + bRd;
#pragma unroll
    for (int kk = 0; kk < 2; ++kk) {                     // khi_loc = kk*4+quad
      short8 af[4], bf[4];
#pragma unroll
      for (int mi = 0; mi < 4; ++mi) {
        // m = wm*64 + mi*16 + l15; A LDS: ch*8192 + khi_loc*1024 + cl*16
        // wm*64 + mi*16: ch = (wm*4+mi)>>2... with wm half: ch = wm? no:
        // m in 0..127 within 128 couts; wm*64: wm picks ch directly when
        // mi<4 (mi*16+l15 < 64) -> ch = wm, cl = mi*16+l15. aRd has wm*8192.
        af[mi] = LD8(Ab + kk * 4096 + mi * 256);
      }
#pragma unroll
      for (int ni = 0; ni < 4; ++ni)
        bf[ni] = LD8(Bb + kk * 4096 + ni * 256);
      __builtin_amdgcn_s_setprio(1);
#pragma unroll
      for (int mi = 0; mi < 4; ++mi)
#pragma unroll
        for (int ni = 0; ni < 4; ++ni)
          acc[mi][ni] = MM(af[mi], bf[ni], acc[mi][ni]);
      __builtin_amdgcn_s_setprio(0);
      SB0;
    }
    asm volatile("s_waitcnt vmcnt(0)" ::: "memory");
    __builtin_amdgcn_s_barrier();
    SB0;
  }

  const int b   = rp / NT_PER_B;
  const int nb0 = (rp % NT_PER_B) * 128;
#pragma unroll
  for (int mi = 0; mi < 4; ++mi) {
    const int co = mtile * 128 + wm * 64 + mi * 16 + quad * 4;  // + reg r
#pragma unroll
    for (int ni = 0; ni < 4; ++ni) {
      const int n = wn * 64 + ni * 16 + l15;
      const int w = n & 63;
      if (w < 56) {
        const int nb = nb0 + n;
        const int h  = nb >> 6;
        floatx4 f = acc[mi][ni];
        const size_t base = (size_t)(b * 256 + co) * 3136 + h * 56 + w;
#pragma unroll
        for (int r = 0; r < 4; ++r)
          out[base + (size_t)r * 3136] = f[r] + fcb[co + r];
      }
    }
  }
}

extern "C" void kernel_launch(void* const* d_in, const int* in_sizes, int n_in,
                              void* d_out, int out_size, void* d_ws, size_t ws_size,
                              hipStream_t stream) {
  const float* x  = (const float*)d_in[0];
  const float* bw = (const float*)d_in[1];
  const float* fw = (const float*)d_in[2];
  const float* fb = (const float*)d_in[3];
  float* out = (float*)d_out;
  char* ws = (char*)d_ws;

  __hip_bfloat16* Wp = (__hip_bfloat16*)(ws + OFF_WP);
  __hip_bfloat16* A2 = (__hip_bfloat16*)(ws + OFF_A2);
  __hip_bfloat16* Xp = (__hip_bfloat16*)(ws + OFF_XP);
  __hip_bfloat16* Y  = (__hip_bfloat16*)(ws + OFF_Y);

  k_wprep<<<dim3(4608), dim3(256), 0, stream>>>(bw, Wp);
  k_a2prep<<<dim3(512), dim3(256), 0, stream>>>(fw, A2);
  k_xprep<<<dim3(14848), dim3(256), 0, stream>>>(x, Xp);
  k_conv1<<<dim3(1792), dim3(256), 0, stream>>>(Xp, Wp, Y);
  k_conv2<<<dim3(1792), dim3(256), 0, stream>>>(Y, A2, fb, out);
}